// Round 13
// baseline (366.840 us; speedup 1.0000x reference)
//
#include <hip/hip_runtime.h>
#include <hip/hip_fp16.h>
#include <math.h>

#define N_NODES 100000
#define N_EDGES 1600000
#define NB 1563          // ceil(N_NODES / 64) buckets, bucket = dst >> 6
#define CAP 2048         // LDS staging per bucket in k_fill2 (mean 1024, sd ~32)
#define NBLK_S 128       // scatter/hist blocks
#define CHUNK (N_EDGES / NBLK_S)   // 12500 edges per block (divides exactly)

typedef _Float16 half8_t __attribute__((ext_vector_type(8)));
typedef float floatx4 __attribute__((ext_vector_type(4)));

// ---------------- counting-sort CSR build ----------------

__global__ __launch_bounds__(1024) void k_hist(const int* __restrict__ dst,
                                               int* __restrict__ ghist) {
    __shared__ int hist[NB];
    int blk = blockIdx.x, t = threadIdx.x;
    for (int i = t; i < NB; i += 1024) hist[i] = 0;
    __syncthreads();
    const int4* dq = (const int4*)(dst + blk * CHUNK);
    const int nq = CHUNK >> 2;
    for (int i = t; i < nq; i += 1024) {
        int4 d = dq[i];
        atomicAdd(&hist[d.x >> 6], 1);
        atomicAdd(&hist[d.y >> 6], 1);
        atomicAdd(&hist[d.z >> 6], 1);
        atomicAdd(&hist[d.w >> 6], 1);
    }
    __syncthreads();
    for (int i = t; i < NB; i += 1024) ghist[i * NBLK_S + blk] = hist[i];
}

__global__ void k_scanb(int* __restrict__ ghist, int* __restrict__ btot) {
    __shared__ int s[NBLK_S];
    int b = blockIdx.x, t = threadIdx.x;
    int v = ghist[b * NBLK_S + t];
    s[t] = v;
    __syncthreads();
    for (int off = 1; off < NBLK_S; off <<= 1) {
        int a = (t >= off) ? s[t - off] : 0;
        __syncthreads();
        s[t] += a;
        __syncthreads();
    }
    ghist[b * NBLK_S + t] = s[t] - v;
    if (t == NBLK_S - 1) btot[b] = s[t];
}

__global__ void k_scant(const int* __restrict__ btot, int* __restrict__ bbase,
                        int* __restrict__ rowptr) {
    __shared__ int s[1024];
    __shared__ int carry;
    int t = threadIdx.x;
    if (t == 0) carry = 0;
    __syncthreads();
    for (int chunk = 0; chunk < 2; ++chunk) {
        int i = chunk * 1024 + t;
        int v = (i < NB) ? btot[i] : 0;
        s[t] = v;
        __syncthreads();
        for (int off = 1; off < 1024; off <<= 1) {
            int a = (t >= off) ? s[t - off] : 0;
            __syncthreads();
            s[t] += a;
            __syncthreads();
        }
        if (i < NB) bbase[i] = carry + s[t] - v;
        int total = carry + s[1023];
        __syncthreads();
        if (t == 0) carry = total;
        __syncthreads();
    }
    if (t == 0) rowptr[N_NODES] = N_EDGES;
}

__global__ __launch_bounds__(1024) void k_scatter(const int* __restrict__ src,
                                                  const int* __restrict__ dst,
                                                  const int* __restrict__ ghist,
                                                  const int* __restrict__ bbase,
                                                  unsigned* __restrict__ bentry) {
    __shared__ int cursor[NB];
    int blk = blockIdx.x, t = threadIdx.x;
    for (int i = t; i < NB; i += 1024)
        cursor[i] = bbase[i] + ghist[i * NBLK_S + blk];
    __syncthreads();
    const int4* dq = (const int4*)(dst + blk * CHUNK);
    const int4* sq = (const int4*)(src + blk * CHUNK);
    const int nq = CHUNK >> 2;
    for (int i = t; i < nq; i += 1024) {
        int4 d = dq[i];
        int4 s = sq[i];
        int p0 = atomicAdd(&cursor[d.x >> 6], 1);
        int p1 = atomicAdd(&cursor[d.y >> 6], 1);
        int p2 = atomicAdd(&cursor[d.z >> 6], 1);
        int p3 = atomicAdd(&cursor[d.w >> 6], 1);
        bentry[p0] = ((unsigned)(d.x & 63) << 17) | (unsigned)s.x;
        bentry[p1] = ((unsigned)(d.y & 63) << 17) | (unsigned)s.y;
        bentry[p2] = ((unsigned)(d.z & 63) << 17) | (unsigned)s.z;
        bentry[p3] = ((unsigned)(d.w & 63) << 17) | (unsigned)s.w;
    }
}

__global__ __launch_bounds__(256) void k_fill2(const int* __restrict__ btot,
                                               const int* __restrict__ bbase,
                                               const unsigned* __restrict__ bentry,
                                               int* __restrict__ rowptr,
                                               float* __restrict__ dinv,
                                               int* __restrict__ colv) {
    __shared__ unsigned ent[CAP];
    __shared__ int hist[64];
    __shared__ int cursor[64];
    int b = blockIdx.x;
    int t = threadIdx.x;
    int cnt = btot[b]; if (cnt > CAP) cnt = CAP;
    int base = bbase[b];
    if (t < 64) hist[t] = 0;
    __syncthreads();
    const unsigned* be = bentry + base;
    for (int i = t; i < cnt; i += 256) {
        unsigned e = be[i];
        ent[i] = e;
        atomicAdd(&hist[e >> 17], 1);
    }
    __syncthreads();
    if (t < 64) {
        int v = hist[t];
        int incl = v;
#pragma unroll
        for (int off = 1; off < 64; off <<= 1) {
            int a = __shfl_up(incl, off);
            if (t >= off) incl += a;
        }
        int excl = incl - v;
        cursor[t] = excl;
        int node = (b << 6) + t;
        if (node < N_NODES) {
            rowptr[node] = base + excl;
            dinv[node] = rsqrtf((float)(v + 1));   // +1 self-loop
        }
    }
    __syncthreads();
    for (int i = t; i < cnt; i += 256) {
        unsigned e = ent[i];
        int pos = base + atomicAdd(&cursor[e >> 17], 1);
        colv[pos] = (int)(e & 0x1FFFF);
    }
}

// ---------------- weight prep: Wt[l][col][k] = (fp16) W[l][k][col] ---------

__global__ void k_prepw(const float* __restrict__ W1, const float* __restrict__ W2,
                        const float* __restrict__ W3, const float* __restrict__ W4,
                        const float* __restrict__ W5, const float* __restrict__ W6,
                        __half* __restrict__ wt) {
    int l = blockIdx.x;
    const float* W = (l == 0) ? W1 : (l == 1) ? W2 : (l == 2) ? W3
                   : (l == 3) ? W4 : (l == 4) ? W5 : W6;
    int din = (l == 0) ? 128 : 64;
    __half* dstp = wt + ((l == 0) ? 0 : 8192 + (l - 1) * 4096);
    int n = 64 * din;
    for (int i = threadIdx.x; i < n; i += blockDim.x) {
        int col = i / din, k = i - col * din;
        dstp[i] = __float2half(W[k * 64 + col]);
    }
}

// ---------------- GEMM0: h' = (x_fp32 @ W1) * dinv, fp16 out --------------
// Wave = 16 nodes x 64 cols via mfma_f32_16x16x32_f16; fp32 input converted
// in-register. D: row=(lane>>4)*4+reg, col=lane&15 (m89-verified). No LDS.

__global__ __launch_bounds__(256) void k_gemm0(const float* __restrict__ in,
                                               const __half* __restrict__ Wt,
                                               const float* __restrict__ dinv,
                                               __half* __restrict__ h) {
    int tid  = threadIdx.x;
    int lane = tid & 63;
    int node0 = blockIdx.x * 64 + (tid >> 6) * 16;
    if (node0 >= N_NODES) return;
    int lr = lane & 15;
    int lk = (lane >> 4) * 8;

    int arow = node0 + lr; if (arow >= N_NODES) arow = N_NODES - 1;
    const float*  ap32 = in + (size_t)arow * 128 + lk;
    const __half* bp = Wt + (size_t)lr * 128 + lk;

    floatx4 acc0 = {0.f, 0.f, 0.f, 0.f}, acc1 = acc0, acc2 = acc0, acc3 = acc0;
#pragma unroll
    for (int kc = 0; kc < 4; ++kc) {
        float4 f0 = *(const float4*)(ap32 + kc * 32);
        float4 f1 = *(const float4*)(ap32 + kc * 32 + 4);
        half8_t a;
        a[0] = (_Float16)f0.x; a[1] = (_Float16)f0.y;
        a[2] = (_Float16)f0.z; a[3] = (_Float16)f0.w;
        a[4] = (_Float16)f1.x; a[5] = (_Float16)f1.y;
        a[6] = (_Float16)f1.z; a[7] = (_Float16)f1.w;
        half8_t b0 = *(const half8_t*)(bp + kc * 32);
        half8_t b1 = *(const half8_t*)(bp + kc * 32 + 16 * 128);
        half8_t b2 = *(const half8_t*)(bp + kc * 32 + 32 * 128);
        half8_t b3 = *(const half8_t*)(bp + kc * 32 + 48 * 128);
        acc0 = __builtin_amdgcn_mfma_f32_16x16x32_f16(a, b0, acc0, 0, 0, 0);
        acc1 = __builtin_amdgcn_mfma_f32_16x16x32_f16(a, b1, acc1, 0, 0, 0);
        acc2 = __builtin_amdgcn_mfma_f32_16x16x32_f16(a, b2, acc2, 0, 0, 0);
        acc3 = __builtin_amdgcn_mfma_f32_16x16x32_f16(a, b3, acc3, 0, 0, 0);
    }

    int rbase = node0 + (lane >> 4) * 4;
#pragma unroll
    for (int r = 0; r < 4; ++r) {
        int row = rbase + r;
        if (row < N_NODES) {
            float dn = dinv[row];
            __half* op = h + ((size_t)row << 6) + lr;
            op[0]  = __float2half(acc0[r] * dn);
            op[16] = __float2half(acc1[r] * dn);
            op[32] = __float2half(acc2[r] * dn);
            op[48] = __float2half(acc3[r] * dn);
        }
    }
}

// ---------------- fused: aggregate_l -> LDS act -> GEMM_{l+1} -------------
// Block = 64 nodes. Phase 1: quarter-wave aggregates 4 nodes (unroll-8 fp16
// gather), relu'd act rows -> LDS [64][80] halves (16B-aligned rows).
// Phase 2: 4 waves MFMA (act @ W_next) * dinv -> h_next. No early returns
// (syncthreads).

__global__ __launch_bounds__(256) void k_fused(const int* __restrict__ rowptr,
                                               const int* __restrict__ colv,
                                               const __half* __restrict__ h,
                                               const float* __restrict__ dinv,
                                               const float* __restrict__ bias,
                                               const __half* __restrict__ Wt,
                                               __half* __restrict__ hn) {
    __shared__ __half sA[64 * 80];
    int tid = threadIdx.x;
    int node0 = blockIdx.x * 64;
    int q = tid >> 4, ql = tid & 15;
    const __half* hp = h + (ql << 2);
    float4 bv = ((const float4*)bias)[ql];
    union UV { uint2 u; __half2 h2[2]; };

    for (int j = 0; j < 4; ++j) {
        int trow = (j << 4) + q;
        int node = node0 + trow;
        uint2* sdst = (uint2*)&sA[trow * 80 + (ql << 2)];
        if (node >= N_NODES) { *sdst = make_uint2(0u, 0u); continue; }
        int beg = rowptr[node], end = rowptr[node + 1];
        __half2 z = __floats2half2_rn(0.f, 0.f);
        __half2 A0 = z, A1 = z, B0 = z, B1 = z, C0 = z, C1 = z, D0 = z, D1 = z;
        int k = beg;
        for (; k + 8 <= end; k += 8) {
            int s0 = colv[k],     s1 = colv[k + 1], s2 = colv[k + 2], s3 = colv[k + 3];
            int s4 = colv[k + 4], s5 = colv[k + 5], s6 = colv[k + 6], s7 = colv[k + 7];
            UV v0, v1, v2, v3, v4, v5, v6, v7;
            v0.u = *(const uint2*)(hp + ((size_t)s0 << 6));
            v1.u = *(const uint2*)(hp + ((size_t)s1 << 6));
            v2.u = *(const uint2*)(hp + ((size_t)s2 << 6));
            v3.u = *(const uint2*)(hp + ((size_t)s3 << 6));
            v4.u = *(const uint2*)(hp + ((size_t)s4 << 6));
            v5.u = *(const uint2*)(hp + ((size_t)s5 << 6));
            v6.u = *(const uint2*)(hp + ((size_t)s6 << 6));
            v7.u = *(const uint2*)(hp + ((size_t)s7 << 6));
            A0 = __hadd2(A0, v0.h2[0]); A1 = __hadd2(A1, v0.h2[1]);
            B0 = __hadd2(B0, v1.h2[0]); B1 = __hadd2(B1, v1.h2[1]);
            C0 = __hadd2(C0, v2.h2[0]); C1 = __hadd2(C1, v2.h2[1]);
            D0 = __hadd2(D0, v3.h2[0]); D1 = __hadd2(D1, v3.h2[1]);
            A0 = __hadd2(A0, v4.h2[0]); A1 = __hadd2(A1, v4.h2[1]);
            B0 = __hadd2(B0, v5.h2[0]); B1 = __hadd2(B1, v5.h2[1]);
            C0 = __hadd2(C0, v6.h2[0]); C1 = __hadd2(C1, v6.h2[1]);
            D0 = __hadd2(D0, v7.h2[0]); D1 = __hadd2(D1, v7.h2[1]);
        }
        for (; k + 4 <= end; k += 4) {
            int s0 = colv[k], s1 = colv[k + 1], s2 = colv[k + 2], s3 = colv[k + 3];
            UV v0, v1, v2, v3;
            v0.u = *(const uint2*)(hp + ((size_t)s0 << 6));
            v1.u = *(const uint2*)(hp + ((size_t)s1 << 6));
            v2.u = *(const uint2*)(hp + ((size_t)s2 << 6));
            v3.u = *(const uint2*)(hp + ((size_t)s3 << 6));
            A0 = __hadd2(A0, v0.h2[0]); A1 = __hadd2(A1, v0.h2[1]);
            B0 = __hadd2(B0, v1.h2[0]); B1 = __hadd2(B1, v1.h2[1]);
            C0 = __hadd2(C0, v2.h2[0]); C1 = __hadd2(C1, v2.h2[1]);
            D0 = __hadd2(D0, v3.h2[0]); D1 = __hadd2(D1, v3.h2[1]);
        }
        for (; k < end; ++k) {
            int s0 = colv[k];
            UV v0;
            v0.u = *(const uint2*)(hp + ((size_t)s0 << 6));
            A0 = __hadd2(A0, v0.h2[0]); A1 = __hadd2(A1, v0.h2[1]);
        }
        A0 = __hadd2(__hadd2(A0, B0), __hadd2(C0, D0));
        A1 = __hadd2(__hadd2(A1, B1), __hadd2(C1, D1));

        float2 f0 = __half22float2(A0), f1 = __half22float2(A1);
        UV sv;
        sv.u = *(const uint2*)(hp + ((size_t)node << 6));
        float2 s0f = __half22float2(sv.h2[0]), s1f = __half22float2(sv.h2[1]);
        float dn = dinv[node];
        float r0 = fmaxf(fmaf(f0.x + s0f.x, dn, bv.x), 0.f);
        float r1 = fmaxf(fmaf(f0.y + s0f.y, dn, bv.y), 0.f);
        float r2 = fmaxf(fmaf(f1.x + s1f.x, dn, bv.z), 0.f);
        float r3 = fmaxf(fmaf(f1.y + s1f.y, dn, bv.w), 0.f);
        UV pk;
        pk.h2[0] = __floats2half2_rn(r0, r1);
        pk.h2[1] = __floats2half2_rn(r2, r3);
        *sdst = pk.u;
    }
    __syncthreads();

    // GEMM phase: act (LDS) @ Wt -> hn
    int lane = tid & 63;
    int lr = lane & 15;
    int lk = (lane >> 4) * 8;
    int wrow0 = (tid >> 6) * 16;
    const __half* bp = Wt + (size_t)lr * 64 + lk;

    floatx4 acc0 = {0.f, 0.f, 0.f, 0.f}, acc1 = acc0, acc2 = acc0, acc3 = acc0;
#pragma unroll
    for (int kc = 0; kc < 2; ++kc) {
        half8_t a  = *(const half8_t*)&sA[(wrow0 + lr) * 80 + kc * 32 + lk];
        half8_t b0 = *(const half8_t*)(bp + kc * 32);
        half8_t b1 = *(const half8_t*)(bp + kc * 32 + 16 * 64);
        half8_t b2 = *(const half8_t*)(bp + kc * 32 + 32 * 64);
        half8_t b3 = *(const half8_t*)(bp + kc * 32 + 48 * 64);
        acc0 = __builtin_amdgcn_mfma_f32_16x16x32_f16(a, b0, acc0, 0, 0, 0);
        acc1 = __builtin_amdgcn_mfma_f32_16x16x32_f16(a, b1, acc1, 0, 0, 0);
        acc2 = __builtin_amdgcn_mfma_f32_16x16x32_f16(a, b2, acc2, 0, 0, 0);
        acc3 = __builtin_amdgcn_mfma_f32_16x16x32_f16(a, b3, acc3, 0, 0, 0);
    }

    int rbase = node0 + wrow0 + (lane >> 4) * 4;
#pragma unroll
    for (int r = 0; r < 4; ++r) {
        int row = rbase + r;
        if (row < N_NODES) {
            float dn = dinv[row];
            __half* op = hn + ((size_t)row << 6) + lr;
            op[0]  = __float2half(acc0[r] * dn);
            op[16] = __float2half(acc1[r] * dn);
            op[32] = __float2half(acc2[r] * dn);
            op[48] = __float2half(acc3[r] * dn);
        }
    }
}

// ---------------- final aggregate + log-softmax ----------------

__global__ __launch_bounds__(256) void k_aggsm(const int* __restrict__ rowptr,
                                               const int* __restrict__ colv,
                                               const __half* __restrict__ h,
                                               const float* __restrict__ dinv,
                                               const float* __restrict__ bias,
                                               float* __restrict__ outf) {
    int tid  = threadIdx.x;
    int node = blockIdx.x * 16 + (tid >> 4);
    if (node >= N_NODES) return;
    int ql = tid & 15;

    int beg = rowptr[node], end = rowptr[node + 1];
    const __half* hp = h + (ql << 2);

    __half2 z = __floats2half2_rn(0.f, 0.f);
    __half2 A0 = z, A1 = z, B0 = z, B1 = z, C0 = z, C1 = z, D0 = z, D1 = z;
    union UV { uint2 u; __half2 h2[2]; };
    int k = beg;
    for (; k + 8 <= end; k += 8) {
        int s0 = colv[k],     s1 = colv[k + 1], s2 = colv[k + 2], s3 = colv[k + 3];
        int s4 = colv[k + 4], s5 = colv[k + 5], s6 = colv[k + 6], s7 = colv[k + 7];
        UV v0, v1, v2, v3, v4, v5, v6, v7;
        v0.u = *(const uint2*)(hp + ((size_t)s0 << 6));
        v1.u = *(const uint2*)(hp + ((size_t)s1 << 6));
        v2.u = *(const uint2*)(hp + ((size_t)s2 << 6));
        v3.u = *(const uint2*)(hp + ((size_t)s3 << 6));
        v4.u = *(const uint2*)(hp + ((size_t)s4 << 6));
        v5.u = *(const uint2*)(hp + ((size_t)s5 << 6));
        v6.u = *(const uint2*)(hp + ((size_t)s6 << 6));
        v7.u = *(const uint2*)(hp + ((size_t)s7 << 6));
        A0 = __hadd2(A0, v0.h2[0]); A1 = __hadd2(A1, v0.h2[1]);
        B0 = __hadd2(B0, v1.h2[0]); B1 = __hadd2(B1, v1.h2[1]);
        C0 = __hadd2(C0, v2.h2[0]); C1 = __hadd2(C1, v2.h2[1]);
        D0 = __hadd2(D0, v3.h2[0]); D1 = __hadd2(D1, v3.h2[1]);
        A0 = __hadd2(A0, v4.h2[0]); A1 = __hadd2(A1, v4.h2[1]);
        B0 = __hadd2(B0, v5.h2[0]); B1 = __hadd2(B1, v5.h2[1]);
        C0 = __hadd2(C0, v6.h2[0]); C1 = __hadd2(C1, v6.h2[1]);
        D0 = __hadd2(D0, v7.h2[0]); D1 = __hadd2(D1, v7.h2[1]);
    }
    for (; k + 4 <= end; k += 4) {
        int s0 = colv[k], s1 = colv[k + 1], s2 = colv[k + 2], s3 = colv[k + 3];
        UV v0, v1, v2, v3;
        v0.u = *(const uint2*)(hp + ((size_t)s0 << 6));
        v1.u = *(const uint2*)(hp + ((size_t)s1 << 6));
        v2.u = *(const uint2*)(hp + ((size_t)s2 << 6));
        v3.u = *(const uint2*)(hp + ((size_t)s3 << 6));
        A0 = __hadd2(A0, v0.h2[0]); A1 = __hadd2(A1, v0.h2[1]);
        B0 = __hadd2(B0, v1.h2[0]); B1 = __hadd2(B1, v1.h2[1]);
        C0 = __hadd2(C0, v2.h2[0]); C1 = __hadd2(C1, v2.h2[1]);
        D0 = __hadd2(D0, v3.h2[0]); D1 = __hadd2(D1, v3.h2[1]);
    }
    for (; k < end; ++k) {
        int s0 = colv[k];
        UV v0;
        v0.u = *(const uint2*)(hp + ((size_t)s0 << 6));
        A0 = __hadd2(A0, v0.h2[0]); A1 = __hadd2(A1, v0.h2[1]);
    }
    A0 = __hadd2(__hadd2(A0, B0), __hadd2(C0, D0));
    A1 = __hadd2(__hadd2(A1, B1), __hadd2(C1, D1));

    float2 f0 = __half22float2(A0), f1 = __half22float2(A1);
    UV sv;
    sv.u = *(const uint2*)(hp + ((size_t)node << 6));
    float2 s0f = __half22float2(sv.h2[0]), s1f = __half22float2(sv.h2[1]);
    float dn = dinv[node];
    float4 bv = ((const float4*)bias)[ql];
    float r0 = fmaxf(fmaf(f0.x + s0f.x, dn, bv.x), 0.f);
    float r1 = fmaxf(fmaf(f0.y + s0f.y, dn, bv.y), 0.f);
    float r2 = fmaxf(fmaf(f1.x + s1f.x, dn, bv.z), 0.f);
    float r3 = fmaxf(fmaf(f1.y + s1f.y, dn, bv.w), 0.f);

    float m = fmaxf(fmaxf(r0, r1), fmaxf(r2, r3));
#pragma unroll
    for (int off = 1; off <= 8; off <<= 1) m = fmaxf(m, __shfl_xor(m, off));
    float ss = expf(r0 - m) + expf(r1 - m) + expf(r2 - m) + expf(r3 - m);
#pragma unroll
    for (int off = 1; off <= 8; off <<= 1) ss += __shfl_xor(ss, off);
    float lse = m + logf(ss);
    *(float4*)(outf + ((size_t)node << 6) + (ql << 2)) =
        make_float4(r0 - lse, r1 - lse, r2 - lse, r3 - lse);
}

// ---------------- launch ----------------

extern "C" void kernel_launch(void* const* d_in, const int* in_sizes, int n_in,
                              void* d_out, int out_size, void* d_ws, size_t ws_size,
                              hipStream_t stream) {
    const float* x = (const float*)d_in[0];
    const int* ei  = (const int*)d_in[1];   // harness delivers integers as int32
    const int* src = ei;
    const int* dst = ei + N_EDGES;

    const float* W[6];
    const float* b[6];
    for (int i = 0; i < 6; ++i) {
        W[i] = (const float*)d_in[2 + 2 * i];
        b[i] = (const float*)d_in[3 + 2 * i];
    }
    float* out = (float*)d_out;

    // workspace: hA | hB | wt | rowptr | dinv | colv
    // build-only arrays alias the hA region (dead until gemm0).
    char* p = (char*)d_ws;
    __half* hA     = (__half*)p; p += (size_t)N_NODES * 64 * 2;    // 12.8 MB
    __half* hB     = (__half*)p; p += (size_t)N_NODES * 64 * 2;    // 12.8 MB
    __half* wt     = (__half*)p; p += 28672 * 2;                   // 56 KB
    int*    rowptr = (int*)p;    p += (size_t)(N_NODES + 1) * 4;
    float*  dinv   = (float*)p;  p += (size_t)N_NODES * 4;
    int*    colv   = (int*)p;
    unsigned* bentry = (unsigned*)hA;                      // 6.4 MB (aliases hA)
    int*    ghist = (int*)(bentry + (size_t)N_EDGES);      // NB*128 ints (800 KB)
    int*    btot  = ghist + (size_t)NB * NBLK_S;
    int*    bbase = btot + NB;

    const int nb_q    = (N_NODES + 15) / 16;    // final agg: 1 node/quarter-wave
    const int nb_tile = (N_NODES + 63) / 64;    // gemm/fused: 64 nodes/block

    // weight prep (independent of build)
    k_prepw<<<6, 256, 0, stream>>>(W[0], W[1], W[2], W[3], W[4], W[5], wt);

    // CSR build: counting sort by bucket, then in-bucket refine.
    k_hist<<<NBLK_S, 1024, 0, stream>>>(dst, ghist);
    k_scanb<<<NB, NBLK_S, 0, stream>>>(ghist, btot);
    k_scant<<<1, 1024, 0, stream>>>(btot, bbase, rowptr);
    k_scatter<<<NBLK_S, 1024, 0, stream>>>(src, dst, ghist, bbase, bentry);
    k_fill2<<<NB, 256, 0, stream>>>(btot, bbase, bentry, rowptr, dinv, colv);

    // layer pipeline: gemm0 -> 5x fused(agg_l + gemm_{l+1}) -> final agg+lsm
    k_gemm0<<<nb_tile, 256, 0, stream>>>(x, wt, dinv, hA);
    __half* hc = hA;
    __half* hn = hB;
    for (int l = 1; l <= 5; ++l) {
        k_fused<<<nb_tile, 256, 0, stream>>>(rowptr, colv, hc, dinv, b[l - 1],
                                             wt + 8192 + (l - 1) * 4096, hn);
        __half* tswap = hc; hc = hn; hn = tswap;
    }
    k_aggsm<<<nb_q, 256, 0, stream>>>(rowptr, colv, hc, dinv, b[5], out);
}

// Round 14
// 339.135 us; speedup vs baseline: 1.0817x; 1.0817x over previous
//
#include <hip/hip_runtime.h>
#include <hip/hip_fp16.h>
#include <math.h>

#define N_NODES 100000
#define N_EDGES 1600000
#define NB 1563          // ceil(N_NODES / 64) buckets, bucket = dst >> 6
#define CAP 2048         // LDS staging per bucket in k_fill2 (mean 1024, sd ~32)
#define NBLK_S 128       // scatter/hist blocks
#define CHUNK (N_EDGES / NBLK_S)   // 12500 edges per block (divides exactly)

typedef _Float16 half8_t __attribute__((ext_vector_type(8)));
typedef float floatx4 __attribute__((ext_vector_type(4)));

// ---------------- counting-sort CSR build ----------------

__global__ __launch_bounds__(1024) void k_hist(const int* __restrict__ dst,
                                               int* __restrict__ ghist) {
    __shared__ int hist[NB];
    int blk = blockIdx.x, t = threadIdx.x;
    for (int i = t; i < NB; i += 1024) hist[i] = 0;
    __syncthreads();
    const int4* dq = (const int4*)(dst + blk * CHUNK);
    const int nq = CHUNK >> 2;
    for (int i = t; i < nq; i += 1024) {
        int4 d = dq[i];
        atomicAdd(&hist[d.x >> 6], 1);
        atomicAdd(&hist[d.y >> 6], 1);
        atomicAdd(&hist[d.z >> 6], 1);
        atomicAdd(&hist[d.w >> 6], 1);
    }
    __syncthreads();
    for (int i = t; i < NB; i += 1024) ghist[i * NBLK_S + blk] = hist[i];
}

__global__ void k_scanb(int* __restrict__ ghist, int* __restrict__ btot) {
    __shared__ int s[NBLK_S];
    int b = blockIdx.x, t = threadIdx.x;
    int v = ghist[b * NBLK_S + t];
    s[t] = v;
    __syncthreads();
    for (int off = 1; off < NBLK_S; off <<= 1) {
        int a = (t >= off) ? s[t - off] : 0;
        __syncthreads();
        s[t] += a;
        __syncthreads();
    }
    ghist[b * NBLK_S + t] = s[t] - v;
    if (t == NBLK_S - 1) btot[b] = s[t];
}

__global__ void k_scant(const int* __restrict__ btot, int* __restrict__ bbase,
                        int* __restrict__ rowptr) {
    __shared__ int s[1024];
    __shared__ int carry;
    int t = threadIdx.x;
    if (t == 0) carry = 0;
    __syncthreads();
    for (int chunk = 0; chunk < 2; ++chunk) {
        int i = chunk * 1024 + t;
        int v = (i < NB) ? btot[i] : 0;
        s[t] = v;
        __syncthreads();
        for (int off = 1; off < 1024; off <<= 1) {
            int a = (t >= off) ? s[t - off] : 0;
            __syncthreads();
            s[t] += a;
            __syncthreads();
        }
        if (i < NB) bbase[i] = carry + s[t] - v;
        int total = carry + s[1023];
        __syncthreads();
        if (t == 0) carry = total;
        __syncthreads();
    }
    if (t == 0) rowptr[N_NODES] = N_EDGES;
}

__global__ __launch_bounds__(1024) void k_scatter(const int* __restrict__ src,
                                                  const int* __restrict__ dst,
                                                  const int* __restrict__ ghist,
                                                  const int* __restrict__ bbase,
                                                  unsigned* __restrict__ bentry) {
    __shared__ int cursor[NB];
    int blk = blockIdx.x, t = threadIdx.x;
    for (int i = t; i < NB; i += 1024)
        cursor[i] = bbase[i] + ghist[i * NBLK_S + blk];
    __syncthreads();
    const int4* dq = (const int4*)(dst + blk * CHUNK);
    const int4* sq = (const int4*)(src + blk * CHUNK);
    const int nq = CHUNK >> 2;
    for (int i = t; i < nq; i += 1024) {
        int4 d = dq[i];
        int4 s = sq[i];
        int p0 = atomicAdd(&cursor[d.x >> 6], 1);
        int p1 = atomicAdd(&cursor[d.y >> 6], 1);
        int p2 = atomicAdd(&cursor[d.z >> 6], 1);
        int p3 = atomicAdd(&cursor[d.w >> 6], 1);
        bentry[p0] = ((unsigned)(d.x & 63) << 17) | (unsigned)s.x;
        bentry[p1] = ((unsigned)(d.y & 63) << 17) | (unsigned)s.y;
        bentry[p2] = ((unsigned)(d.z & 63) << 17) | (unsigned)s.z;
        bentry[p3] = ((unsigned)(d.w & 63) << 17) | (unsigned)s.w;
    }
}

__global__ __launch_bounds__(256) void k_fill2(const int* __restrict__ btot,
                                               const int* __restrict__ bbase,
                                               const unsigned* __restrict__ bentry,
                                               int* __restrict__ rowptr,
                                               float* __restrict__ dinv,
                                               int* __restrict__ colv) {
    __shared__ unsigned ent[CAP];
    __shared__ int hist[64];
    __shared__ int cursor[64];
    int b = blockIdx.x;
    int t = threadIdx.x;
    int cnt = btot[b]; if (cnt > CAP) cnt = CAP;
    int base = bbase[b];
    if (t < 64) hist[t] = 0;
    __syncthreads();
    const unsigned* be = bentry + base;
    for (int i = t; i < cnt; i += 256) {
        unsigned e = be[i];
        ent[i] = e;
        atomicAdd(&hist[e >> 17], 1);
    }
    __syncthreads();
    if (t < 64) {
        int v = hist[t];
        int incl = v;
#pragma unroll
        for (int off = 1; off < 64; off <<= 1) {
            int a = __shfl_up(incl, off);
            if (t >= off) incl += a;
        }
        int excl = incl - v;
        cursor[t] = excl;
        int node = (b << 6) + t;
        if (node < N_NODES) {
            rowptr[node] = base + excl;
            dinv[node] = rsqrtf((float)(v + 1));   // +1 self-loop
        }
    }
    __syncthreads();
    for (int i = t; i < cnt; i += 256) {
        unsigned e = ent[i];
        int pos = base + atomicAdd(&cursor[e >> 17], 1);
        colv[pos] = (int)(e & 0x1FFFF);
    }
}

// ---------------- weight prep: Wt[l][col][k] = (fp16) W[l][k][col] ---------

__global__ void k_prepw(const float* __restrict__ W1, const float* __restrict__ W2,
                        const float* __restrict__ W3, const float* __restrict__ W4,
                        const float* __restrict__ W5, const float* __restrict__ W6,
                        __half* __restrict__ wt) {
    int l = blockIdx.x;
    const float* W = (l == 0) ? W1 : (l == 1) ? W2 : (l == 2) ? W3
                   : (l == 3) ? W4 : (l == 4) ? W5 : W6;
    int din = (l == 0) ? 128 : 64;
    __half* dstp = wt + ((l == 0) ? 0 : 8192 + (l - 1) * 4096);
    int n = 64 * din;
    for (int i = threadIdx.x; i < n; i += blockDim.x) {
        int col = i / din, k = i - col * din;
        dstp[i] = __float2half(W[k * 64 + col]);
    }
}

// ---------------- MFMA GEMM: h' = (in @ W) * dinv, fp16 out ---------------
// Wave = 16 nodes x 64 cols via 4x mfma_f32_16x16x32_f16 per K-chunk.
// F32IN=1 (layer 0): read fp32 x, convert to half8 in-register.
// D: row=(lane>>4)*4+reg, col=lane&15 (m89-verified). No LDS.

template<int DIN, int F32IN>
__global__ __launch_bounds__(256) void k_gemm(const void* __restrict__ in,
                                              const __half* __restrict__ Wt,
                                              const float* __restrict__ dinv,
                                              __half* __restrict__ h) {
    int tid  = threadIdx.x;
    int lane = tid & 63;
    int node0 = blockIdx.x * 64 + (tid >> 6) * 16;
    if (node0 >= N_NODES) return;
    int lr = lane & 15;
    int lk = (lane >> 4) * 8;

    int arow = node0 + lr; if (arow >= N_NODES) arow = N_NODES - 1;
    const __half* ap  = (const __half*)in + (size_t)arow * DIN + lk;
    const float*  ap32 = (const float*)in + (size_t)arow * DIN + lk;
    const __half* bp = Wt + (size_t)lr * DIN + lk;

    floatx4 acc0 = {0.f, 0.f, 0.f, 0.f}, acc1 = acc0, acc2 = acc0, acc3 = acc0;
#pragma unroll
    for (int kc = 0; kc < DIN / 32; ++kc) {
        half8_t a;
        if (F32IN) {
            float4 f0 = *(const float4*)(ap32 + kc * 32);
            float4 f1 = *(const float4*)(ap32 + kc * 32 + 4);
            a[0] = (_Float16)f0.x; a[1] = (_Float16)f0.y;
            a[2] = (_Float16)f0.z; a[3] = (_Float16)f0.w;
            a[4] = (_Float16)f1.x; a[5] = (_Float16)f1.y;
            a[6] = (_Float16)f1.z; a[7] = (_Float16)f1.w;
        } else {
            a = *(const half8_t*)(ap + kc * 32);
        }
        half8_t b0 = *(const half8_t*)(bp + kc * 32);
        half8_t b1 = *(const half8_t*)(bp + kc * 32 + 16 * DIN);
        half8_t b2 = *(const half8_t*)(bp + kc * 32 + 32 * DIN);
        half8_t b3 = *(const half8_t*)(bp + kc * 32 + 48 * DIN);
        acc0 = __builtin_amdgcn_mfma_f32_16x16x32_f16(a, b0, acc0, 0, 0, 0);
        acc1 = __builtin_amdgcn_mfma_f32_16x16x32_f16(a, b1, acc1, 0, 0, 0);
        acc2 = __builtin_amdgcn_mfma_f32_16x16x32_f16(a, b2, acc2, 0, 0, 0);
        acc3 = __builtin_amdgcn_mfma_f32_16x16x32_f16(a, b3, acc3, 0, 0, 0);
    }

    int rbase = node0 + (lane >> 4) * 4;
#pragma unroll
    for (int r = 0; r < 4; ++r) {
        int row = rbase + r;
        if (row < N_NODES) {
            float dn = dinv[row];
            __half* op = h + ((size_t)row << 6) + lr;
            op[0]  = __float2half(acc0[r] * dn);
            op[16] = __float2half(acc1[r] * dn);
            op[32] = __float2half(acc2[r] * dn);
            op[48] = __float2half(acc3[r] * dn);
        }
    }
}

// ---------------- fused aggregate (fp16 gather, packed fp16 accumulate) ---
// 8-lane group per node (32 nodes/block); lane owns 8 columns (16B of each
// 128B row) -> one uint4 gather per edge per lane. Unroll x8: 8 independent
// 16B loads in flight (128B/lane outstanding). fp32 epilogue.

template<int LAST>
__global__ __launch_bounds__(256) void k_aggregate(const int* __restrict__ rowptr,
                                                   const int* __restrict__ colv,
                                                   const __half* __restrict__ h,
                                                   const float* __restrict__ dinv,
                                                   const float* __restrict__ bias,
                                                   __half* __restrict__ acta,
                                                   float* __restrict__ outf) {
    int tid  = threadIdx.x;
    int node = blockIdx.x * 32 + (tid >> 3);
    if (node >= N_NODES) return;
    int gl = tid & 7;                           // owns cols gl*8 .. gl*8+7

    int beg = rowptr[node], end = rowptr[node + 1];
    const __half* hp = h + (gl << 3);

    union UV { uint4 u; __half2 h2[4]; };
    __half2 z = __floats2half2_rn(0.f, 0.f);
    __half2 A0 = z, A1 = z, A2 = z, A3 = z;
    __half2 B0 = z, B1 = z, B2 = z, B3 = z;
    int k = beg;
    for (; k + 8 <= end; k += 8) {
        int s0 = colv[k],     s1 = colv[k + 1], s2 = colv[k + 2], s3 = colv[k + 3];
        int s4 = colv[k + 4], s5 = colv[k + 5], s6 = colv[k + 6], s7 = colv[k + 7];
        UV v0, v1, v2, v3, v4, v5, v6, v7;
        v0.u = *(const uint4*)(hp + ((size_t)s0 << 6));
        v1.u = *(const uint4*)(hp + ((size_t)s1 << 6));
        v2.u = *(const uint4*)(hp + ((size_t)s2 << 6));
        v3.u = *(const uint4*)(hp + ((size_t)s3 << 6));
        v4.u = *(const uint4*)(hp + ((size_t)s4 << 6));
        v5.u = *(const uint4*)(hp + ((size_t)s5 << 6));
        v6.u = *(const uint4*)(hp + ((size_t)s6 << 6));
        v7.u = *(const uint4*)(hp + ((size_t)s7 << 6));
        A0 = __hadd2(A0, v0.h2[0]); A1 = __hadd2(A1, v0.h2[1]);
        A2 = __hadd2(A2, v0.h2[2]); A3 = __hadd2(A3, v0.h2[3]);
        B0 = __hadd2(B0, v1.h2[0]); B1 = __hadd2(B1, v1.h2[1]);
        B2 = __hadd2(B2, v1.h2[2]); B3 = __hadd2(B3, v1.h2[3]);
        A0 = __hadd2(A0, v2.h2[0]); A1 = __hadd2(A1, v2.h2[1]);
        A2 = __hadd2(A2, v2.h2[2]); A3 = __hadd2(A3, v2.h2[3]);
        B0 = __hadd2(B0, v3.h2[0]); B1 = __hadd2(B1, v3.h2[1]);
        B2 = __hadd2(B2, v3.h2[2]); B3 = __hadd2(B3, v3.h2[3]);
        A0 = __hadd2(A0, v4.h2[0]); A1 = __hadd2(A1, v4.h2[1]);
        A2 = __hadd2(A2, v4.h2[2]); A3 = __hadd2(A3, v4.h2[3]);
        B0 = __hadd2(B0, v5.h2[0]); B1 = __hadd2(B1, v5.h2[1]);
        B2 = __hadd2(B2, v5.h2[2]); B3 = __hadd2(B3, v5.h2[3]);
        A0 = __hadd2(A0, v6.h2[0]); A1 = __hadd2(A1, v6.h2[1]);
        A2 = __hadd2(A2, v6.h2[2]); A3 = __hadd2(A3, v6.h2[3]);
        B0 = __hadd2(B0, v7.h2[0]); B1 = __hadd2(B1, v7.h2[1]);
        B2 = __hadd2(B2, v7.h2[2]); B3 = __hadd2(B3, v7.h2[3]);
    }
    for (; k + 4 <= end; k += 4) {
        int s0 = colv[k], s1 = colv[k + 1], s2 = colv[k + 2], s3 = colv[k + 3];
        UV v0, v1, v2, v3;
        v0.u = *(const uint4*)(hp + ((size_t)s0 << 6));
        v1.u = *(const uint4*)(hp + ((size_t)s1 << 6));
        v2.u = *(const uint4*)(hp + ((size_t)s2 << 6));
        v3.u = *(const uint4*)(hp + ((size_t)s3 << 6));
        A0 = __hadd2(A0, v0.h2[0]); A1 = __hadd2(A1, v0.h2[1]);
        A2 = __hadd2(A2, v0.h2[2]); A3 = __hadd2(A3, v0.h2[3]);
        B0 = __hadd2(B0, v1.h2[0]); B1 = __hadd2(B1, v1.h2[1]);
        B2 = __hadd2(B2, v1.h2[2]); B3 = __hadd2(B3, v1.h2[3]);
        A0 = __hadd2(A0, v2.h2[0]); A1 = __hadd2(A1, v2.h2[1]);
        A2 = __hadd2(A2, v2.h2[2]); A3 = __hadd2(A3, v2.h2[3]);
        B0 = __hadd2(B0, v3.h2[0]); B1 = __hadd2(B1, v3.h2[1]);
        B2 = __hadd2(B2, v3.h2[2]); B3 = __hadd2(B3, v3.h2[3]);
    }
    for (; k < end; ++k) {
        int s0 = colv[k];
        UV v0;
        v0.u = *(const uint4*)(hp + ((size_t)s0 << 6));
        A0 = __hadd2(A0, v0.h2[0]); A1 = __hadd2(A1, v0.h2[1]);
        A2 = __hadd2(A2, v0.h2[2]); A3 = __hadd2(A3, v0.h2[3]);
    }
    A0 = __hadd2(A0, B0); A1 = __hadd2(A1, B1);
    A2 = __hadd2(A2, B2); A3 = __hadd2(A3, B3);

    // fp32 epilogue: self-loop + normalize + bias + relu
    UV sv;
    sv.u = *(const uint4*)(hp + ((size_t)node << 6));
    float dn = dinv[node];
    float4 bv0 = ((const float4*)bias)[gl * 2];
    float4 bv1 = ((const float4*)bias)[gl * 2 + 1];
    float2 f0 = __half22float2(A0), f1 = __half22float2(A1);
    float2 f2 = __half22float2(A2), f3 = __half22float2(A3);
    float2 s0f = __half22float2(sv.h2[0]), s1f = __half22float2(sv.h2[1]);
    float2 s2f = __half22float2(sv.h2[2]), s3f = __half22float2(sv.h2[3]);
    float r0 = fmaxf(fmaf(f0.x + s0f.x, dn, bv0.x), 0.f);
    float r1 = fmaxf(fmaf(f0.y + s0f.y, dn, bv0.y), 0.f);
    float r2 = fmaxf(fmaf(f1.x + s1f.x, dn, bv0.z), 0.f);
    float r3 = fmaxf(fmaf(f1.y + s1f.y, dn, bv0.w), 0.f);
    float r4 = fmaxf(fmaf(f2.x + s2f.x, dn, bv1.x), 0.f);
    float r5 = fmaxf(fmaf(f2.y + s2f.y, dn, bv1.y), 0.f);
    float r6 = fmaxf(fmaf(f3.x + s3f.x, dn, bv1.z), 0.f);
    float r7 = fmaxf(fmaf(f3.y + s3f.y, dn, bv1.w), 0.f);

    if (LAST) {
        // log-softmax: 8 values per lane, reduce across the 8-lane group
        float m = fmaxf(fmaxf(fmaxf(r0, r1), fmaxf(r2, r3)),
                        fmaxf(fmaxf(r4, r5), fmaxf(r6, r7)));
#pragma unroll
        for (int off = 1; off <= 4; off <<= 1) m = fmaxf(m, __shfl_xor(m, off));
        float ss = expf(r0 - m) + expf(r1 - m) + expf(r2 - m) + expf(r3 - m)
                 + expf(r4 - m) + expf(r5 - m) + expf(r6 - m) + expf(r7 - m);
#pragma unroll
        for (int off = 1; off <= 4; off <<= 1) ss += __shfl_xor(ss, off);
        float lse = m + logf(ss);
        float* dp = outf + ((size_t)node << 6) + (gl << 3);
        *(float4*)dp       = make_float4(r0 - lse, r1 - lse, r2 - lse, r3 - lse);
        *(float4*)(dp + 4) = make_float4(r4 - lse, r5 - lse, r6 - lse, r7 - lse);
    } else {
        UV pk;
        pk.h2[0] = __floats2half2_rn(r0, r1);
        pk.h2[1] = __floats2half2_rn(r2, r3);
        pk.h2[2] = __floats2half2_rn(r4, r5);
        pk.h2[3] = __floats2half2_rn(r6, r7);
        *(uint4*)(acta + ((size_t)node << 6) + (gl << 3)) = pk.u;
    }
}

// ---------------- launch ----------------

extern "C" void kernel_launch(void* const* d_in, const int* in_sizes, int n_in,
                              void* d_out, int out_size, void* d_ws, size_t ws_size,
                              hipStream_t stream) {
    const float* x = (const float*)d_in[0];
    const int* ei  = (const int*)d_in[1];   // harness delivers integers as int32
    const int* src = ei;
    const int* dst = ei + N_EDGES;

    const float* W[6];
    const float* b[6];
    for (int i = 0; i < 6; ++i) {
        W[i] = (const float*)d_in[2 + 2 * i];
        b[i] = (const float*)d_in[3 + 2 * i];
    }
    float* out = (float*)d_out;

    // workspace: h | act | wt | rowptr | dinv | colv
    // build-only arrays alias the h region (dead until first GEMM).
    char* p = (char*)d_ws;
    __half* h      = (__half*)p; p += (size_t)N_NODES * 64 * 2;    // 12.8 MB
    __half* act    = (__half*)p; p += (size_t)N_NODES * 64 * 2;    // 12.8 MB
    __half* wt     = (__half*)p; p += 28672 * 2;                   // 56 KB
    int*    rowptr = (int*)p;    p += (size_t)(N_NODES + 1) * 4;
    float*  dinv   = (float*)p;  p += (size_t)N_NODES * 4;
    int*    colv   = (int*)p;
    unsigned* bentry = (unsigned*)h;                       // 6.4 MB (aliases h)
    int*    ghist = (int*)(bentry + (size_t)N_EDGES);      // NB*128 ints (800 KB)
    int*    btot  = ghist + (size_t)NB * NBLK_S;
    int*    bbase = btot + NB;

    const int nb_g    = (N_NODES + 31) / 32;    // aggregate: 1 node/8-lane group
    const int nb_tile = (N_NODES + 63) / 64;    // gemm: 64 nodes/block

    // weight prep (independent of build)
    k_prepw<<<6, 256, 0, stream>>>(W[0], W[1], W[2], W[3], W[4], W[5], wt);

    // CSR build: counting sort by bucket, then in-bucket refine.
    k_hist<<<NBLK_S, 1024, 0, stream>>>(dst, ghist);
    k_scanb<<<NB, NBLK_S, 0, stream>>>(ghist, btot);
    k_scant<<<1, 1024, 0, stream>>>(btot, bbase, rowptr);
    k_scatter<<<NBLK_S, 1024, 0, stream>>>(src, dst, ghist, bbase, bentry);
    k_fill2<<<NB, 256, 0, stream>>>(btot, bbase, bentry, rowptr, dinv, colv);

    // 6 GCN layers; gemm(in -> h), aggregate(h -> act / d_out)
    for (int l = 0; l < 6; ++l) {
        if (l == 0)
            k_gemm<128, 1><<<nb_tile, 256, 0, stream>>>(x, wt, dinv, h);
        else
            k_gemm<64, 0><<<nb_tile, 256, 0, stream>>>(act, wt + 8192 + (l - 1) * 4096, dinv, h);
        if (l == 5)
            k_aggregate<1><<<nb_g, 256, 0, stream>>>(rowptr, colv, h, dinv, b[l], act, out);
        else
            k_aggregate<0><<<nb_g, 256, 0, stream>>>(rowptr, colv, h, dinv, b[l], act, out);
    }
}